// Round 1
// baseline (281.527 us; speedup 1.0000x reference)
//
#include <hip/hip_runtime.h>
#include <hip/hip_bf16.h>

// MyConv1d_ell_2_sequential: B=16384, C=128, O=128, LIN=18, out (B,128,54) fp32.
// Decomposition: out[b,o,t*6+l] = sum over tap instances (j, i=2t+p, coef) of
//   coef * sum_c x[b,c,i] * Fj[c,o],  Fj = 5 tap planes (f2 k=0,1 scaled s2; f3 k=0..2 scaled s3)
// 100 mfma-group instances total (coef-2 entries issued twice).

using short8 = short __attribute__((ext_vector_type(8)));
using f32x4  = float __attribute__((ext_vector_type(4)));

#define DEVINL __device__ __forceinline__

DEVINL unsigned short f2bf(float f) {
    unsigned int u = __float_as_uint(f);
    unsigned int r = u + 0x7FFFu + ((u >> 16) & 1u);   // RNE
    return (unsigned short)(r >> 16);
}

// instance tables: per i (0..14), list of (acc slot, filter plane j)
__constant__ constexpr int START[16] = {0,6,12,18,23,31,37,46,54,63,69,77,82,88,94,100};
__constant__ constexpr int SLOT[100] = {
 0,1,2,3,3,4,
 1,2,3,4,4,5,
 6,7,8,9,9,10,
 7,8,9,10,10,
 0,11,12,13,2,14,14,3,
 12,1,13,14,3,4,
 15,6,16,1,17,8,9,3,4,
 16,7,17,2,9,10,4,5,
 18,11,19,7,13,2,14,9,10,
 19,12,8,14,3,10,
 20,15,12,17,8,14,3,3,
 16,13,9,4,4,
 18,16,13,9,9,4,
 19,17,14,10,10,5,
 20,19,17,14,14,10
};
__constant__ constexpr int JJ[100] = {
 0,0,2,2,2,2,
 0,0,2,2,2,2,
 0,0,2,2,2,2,
 0,0,2,2,2,
 1,0,0,2,3,2,2,3,
 0,1,0,2,3,3,
 0,1,0,1,2,3,3,3,3,
 0,1,0,1,3,3,3,3,
 0,1,0,1,3,4,3,3,3,
 0,1,1,3,4,3,
 0,1,1,3,4,3,4,4,
 1,1,4,4,4,
 1,1,4,4,4,4,
 1,1,4,4,4,4,
 1,1,4,4,4,4
};
// slot -> u (column in 0..53); remaining 33 columns are structural zeros
__constant__ constexpr int UCOL[21] = {0,1,2,3,4,5,6,7,8,9,10,12,13,14,15,18,19,20,24,25,30};

__global__ __launch_bounds__(512, 2)
void conv1d_ell_kernel(const float* __restrict__ x,
                       const float* __restrict__ f2,
                       const float* __restrict__ f3,
                       float* __restrict__ out)
{
    // LDS: x tile, bf16, layout [i(15)][b(16)][c(128)] with XOR swizzle on (b&7)
    __shared__ unsigned short xl[15 * 16 * 128];   // 61440 B

    const int tid  = threadIdx.x;
    const int lane = tid & 63;
    const int wid  = tid >> 6;          // 0..7  -> o tile = wid*16
    const int m    = lane & 15;         // A row / D col component
    const int kblk = lane >> 4;         // 0..3

    const long b_base = (long)blockIdx.x * 16;

    // ---- stage x -> LDS (fp32 -> bf16, transpose (b,c,i)->(i,b,c)) ----
    #pragma unroll
    for (int q = 0; q < 4; ++q) {
        int r = tid + q * 512;          // 0..2047
        int b = r >> 7;                 // 0..15
        int c = r & 127;
        const float* px = x + (b_base + b) * 2304 + (long)c * 18;
        float v[16];
        #pragma unroll
        for (int t = 0; t < 8; ++t) {
            float2 w = reinterpret_cast<const float2*>(px)[t];
            v[2*t] = w.x; v[2*t+1] = w.y;
        }
        #pragma unroll
        for (int i = 0; i < 15; ++i) {
            int idx = (i * 2048 + b * 128 + c) ^ ((b & 7) << 3);
            xl[idx] = f2bf(v[i]);
        }
    }

    // ---- load filter B-fragments (pre-scaled), 5 planes x 4 k-chunks ----
    // B-frag for plane j, chunk q: lane (kblk*16+n) holds Fj[c = q*32+kblk*8+e][o0+n]
    const int oc = wid * 16 + m;        // this lane's o column
    short8 bfrag[5][4];
    #pragma unroll
    for (int j = 0; j < 5; ++j) {
        const float scale = (j < 2) ? 0.0625f : 0.051031036307982884f; // 1/sqrt(256), 1/sqrt(384)
        const float* fp = (j < 2) ? (f2 + (long)oc * 256 + j)
                                  : (f3 + (long)oc * 384 + (j - 2));
        const int st = (j < 2) ? 2 : 3;
        #pragma unroll
        for (int q = 0; q < 4; ++q) {
            short8 v;
            #pragma unroll
            for (int e = 0; e < 8; ++e) {
                int c = q * 32 + kblk * 8 + e;
                v[e] = (short)f2bf(fp[(long)c * st] * scale);
            }
            bfrag[j][q] = v;
        }
    }

    f32x4 acc[21];
    #pragma unroll
    for (int s = 0; s < 21; ++s) acc[s] = (f32x4){0.f, 0.f, 0.f, 0.f};

    __syncthreads();

    // ---- main loop: for each position i, 4 A-frags (k-chunks), then instances ----
    #pragma unroll
    for (int i = 0; i < 15; ++i) {
        short8 a[4];
        #pragma unroll
        for (int q = 0; q < 4; ++q) {
            int c0 = q * 32 + kblk * 8;
            int idx = (i * 2048 + m * 128 + c0) ^ ((m & 7) << 3);
            a[q] = *reinterpret_cast<const short8*>(&xl[idx]);
        }
        #pragma unroll
        for (int n = START[i]; n < START[i + 1]; ++n) {
            const int s = SLOT[n];
            const int j = JJ[n];
            #pragma unroll
            for (int q = 0; q < 4; ++q) {
                acc[s] = __builtin_amdgcn_mfma_f32_16x16x32_bf16(a[q], bfrag[j][q], acc[s], 0, 0, 0);
            }
        }
    }

    // ---- epilogue: D layout col(o)=lane&15, row(b)=(lane>>4)*4 + r ----
    const int g = lane >> 4;
    #pragma unroll
    for (int r = 0; r < 4; ++r) {
        float row[54];
        #pragma unroll
        for (int u = 0; u < 54; ++u) row[u] = 0.f;
        #pragma unroll
        for (int s = 0; s < 21; ++s) row[UCOL[s]] = acc[s][r];

        const long brow = b_base + g * 4 + r;
        float* p = out + (brow * 128 + oc) * 54;
        #pragma unroll
        for (int t = 0; t < 27; ++t) {
            float2 w; w.x = row[2*t]; w.y = row[2*t+1];
            *reinterpret_cast<float2*>(p + 2*t) = w;
        }
    }
}

extern "C" void kernel_launch(void* const* d_in, const int* in_sizes, int n_in,
                              void* d_out, int out_size, void* d_ws, size_t ws_size,
                              hipStream_t stream) {
    const float* x   = (const float*)d_in[0];
    const float* sos = (const float*)d_in[1];
    const float* f2  = (const float*)d_in[2];
    const float* f3  = (const float*)d_in[3];
    float* out = (float*)d_out;

    conv1d_ell_kernel<<<dim3(1024), dim3(512), 0, stream>>>(x, f2, f3, out);

    // output 1: pass-through copy of sum_of_squares (16384 floats)
    hipMemcpyAsync(out + 113246208LL, sos, 16384 * sizeof(float),
                   hipMemcpyDeviceToDevice, stream);
}

// Round 2
// 188.034 us; speedup vs baseline: 1.4972x; 1.4972x over previous
//
#include <hip/hip_runtime.h>
#include <hip/hip_bf16.h>

// MyConv1d_ell_2_sequential: B=16384, C=128, O=128, LIN=18, out (B,128,54) fp32.
// Decomposition: out[b,o,t*6+l] = sum over tap instances (j, i=2t+p, coef) of
//   coef * sum_c x[b,c,i] * Fj[c,o],  Fj = 5 tap planes (f2 k=0,1 scaled s2; f3 k=0..2 scaled s3)
// 100 mfma-group instances total (coef-2 entries issued twice).
// R2: LDS-transpose epilogue -> fully coalesced float4 stores (was: 216B-stride
// float2 scatter, 64 lines/instr, 1.25x write amplification, 286us).

using short8 = short __attribute__((ext_vector_type(8)));
using f32x4  = float __attribute__((ext_vector_type(4)));

#define DEVINL __device__ __forceinline__

DEVINL unsigned short f2bf(float f) {
    unsigned int u = __float_as_uint(f);
    unsigned int r = u + 0x7FFFu + ((u >> 16) & 1u);   // RNE
    return (unsigned short)(r >> 16);
}

// instance tables: per i (0..14), list of (acc slot, filter plane j)
__constant__ constexpr int START[16] = {0,6,12,18,23,31,37,46,54,63,69,77,82,88,94,100};
__constant__ constexpr int SLOT[100] = {
 0,1,2,3,3,4,
 1,2,3,4,4,5,
 6,7,8,9,9,10,
 7,8,9,10,10,
 0,11,12,13,2,14,14,3,
 12,1,13,14,3,4,
 15,6,16,1,17,8,9,3,4,
 16,7,17,2,9,10,4,5,
 18,11,19,7,13,2,14,9,10,
 19,12,8,14,3,10,
 20,15,12,17,8,14,3,3,
 16,13,9,4,4,
 18,16,13,9,9,4,
 19,17,14,10,10,5,
 20,19,17,14,14,10
};
__constant__ constexpr int JJ[100] = {
 0,0,2,2,2,2,
 0,0,2,2,2,2,
 0,0,2,2,2,2,
 0,0,2,2,2,
 1,0,0,2,3,2,2,3,
 0,1,0,2,3,3,
 0,1,0,1,2,3,3,3,3,
 0,1,0,1,3,3,3,3,
 0,1,0,1,3,4,3,3,3,
 0,1,1,3,4,3,
 0,1,1,3,4,3,4,4,
 1,1,4,4,4,
 1,1,4,4,4,4,
 1,1,4,4,4,4,
 1,1,4,4,4,4
};
// slot -> u (column in 0..53); remaining 33 columns are structural zeros
__constant__ constexpr int UCOL[21] = {0,1,2,3,4,5,6,7,8,9,10,12,13,14,15,18,19,20,24,25,30};

__global__ __launch_bounds__(512, 2)
void conv1d_ell_kernel(const float* __restrict__ x,
                       const float* __restrict__ f2,
                       const float* __restrict__ f3,
                       float* __restrict__ out)
{
    // Phase 1: x tile, bf16, layout [i(15)][b(16)][c(128)], XOR-swizzled.  61440 B
    // Phase 2 (epilogue): float buffer [rr(2)][o(128)][u(54)].              55296 B
    __shared__ __align__(16) unsigned char smem[61440];
    unsigned short* xl = reinterpret_cast<unsigned short*>(smem);
    float*          ob = reinterpret_cast<float*>(smem);

    const int tid  = threadIdx.x;
    const int lane = tid & 63;
    const int wid  = tid >> 6;          // 0..7  -> o tile = wid*16
    const int m    = lane & 15;         // A row / D col component
    const int kblk = lane >> 4;         // 0..3
    const int g    = lane >> 4;         // D row group

    const long b_base = (long)blockIdx.x * 16;

    // ---- stage x -> LDS (fp32 -> bf16, transpose (b,c,i)->(i,b,c)) ----
    #pragma unroll
    for (int q = 0; q < 4; ++q) {
        int r = tid + q * 512;          // 0..2047
        int b = r >> 7;                 // 0..15
        int c = r & 127;
        const float* px = x + (b_base + b) * 2304 + (long)c * 18;
        float v[16];
        #pragma unroll
        for (int t = 0; t < 8; ++t) {
            float2 w = reinterpret_cast<const float2*>(px)[t];
            v[2*t] = w.x; v[2*t+1] = w.y;
        }
        #pragma unroll
        for (int i = 0; i < 15; ++i) {
            int idx = (i * 2048 + b * 128 + c) ^ ((b & 7) << 3);
            xl[idx] = f2bf(v[i]);
        }
    }

    // ---- load filter B-fragments (pre-scaled), 5 planes x 4 k-chunks ----
    const int oc = wid * 16 + m;        // this lane's o column
    short8 bfrag[5][4];
    #pragma unroll
    for (int j = 0; j < 5; ++j) {
        const float scale = (j < 2) ? 0.0625f : 0.051031036307982884f; // 1/sqrt(256), 1/sqrt(384)
        const float* fp = (j < 2) ? (f2 + (long)oc * 256 + j)
                                  : (f3 + (long)oc * 384 + (j - 2));
        const int st = (j < 2) ? 2 : 3;
        #pragma unroll
        for (int q = 0; q < 4; ++q) {
            short8 v;
            #pragma unroll
            for (int e = 0; e < 8; ++e) {
                int c = q * 32 + kblk * 8 + e;
                v[e] = (short)f2bf(fp[(long)c * st] * scale);
            }
            bfrag[j][q] = v;
        }
    }

    f32x4 acc[21];
    #pragma unroll
    for (int s = 0; s < 21; ++s) acc[s] = (f32x4){0.f, 0.f, 0.f, 0.f};

    __syncthreads();

    // ---- main loop: for each position i, 4 A-frags (k-chunks), then instances ----
    #pragma unroll
    for (int i = 0; i < 15; ++i) {
        short8 a[4];
        #pragma unroll
        for (int q = 0; q < 4; ++q) {
            int c0 = q * 32 + kblk * 8;
            int idx = (i * 2048 + m * 128 + c0) ^ ((m & 7) << 3);
            a[q] = *reinterpret_cast<const short8*>(&xl[idx]);
        }
        #pragma unroll
        for (int n = START[i]; n < START[i + 1]; ++n) {
            const int s = SLOT[n];
            const int j = JJ[n];
            #pragma unroll
            for (int q = 0; q < 4; ++q) {
                acc[s] = __builtin_amdgcn_mfma_f32_16x16x32_bf16(a[q], bfrag[j][q], acc[s], 0, 0, 0);
            }
        }
    }

    // ---- epilogue: LDS transpose -> coalesced float4 stores ----
    // D layout: lane holds (o = oc, b_local = g*4 + r) for r=0..3 in acc[.][r].
    // Chunk k (0..7) covers block-local rows {2k, 2k+1}; owning lanes g == k>>1.
    __syncthreads();                    // all a-frag LDS reads done; safe to reuse

    // zero-fill once: structural-zero columns persist across chunks
    for (int v = tid; v < 3456; v += 512)
        *reinterpret_cast<float4*>(ob + 4 * v) = make_float4(0.f, 0.f, 0.f, 0.f);
    __syncthreads();

    #pragma unroll
    for (int k = 0; k < 8; ++k) {
        if (g == (k >> 1)) {
            #pragma unroll
            for (int rr = 0; rr < 2; ++rr) {
                const int r = 2 * (k & 1) + rr;          // acc register index
                float* dst = ob + (rr * 128 + oc) * 54;  // bank stride 54: conflict-free
                #pragma unroll
                for (int s = 0; s < 21; ++s) dst[UCOL[s]] = acc[s][r];
            }
        }
        __syncthreads();
        // 2 adjacent b-rows = one contiguous 55296-B global region
        float* obase = out + (b_base + 2 * k) * 6912;
        for (int v = tid; v < 3456; v += 512) {
            float4 w = *reinterpret_cast<const float4*>(ob + 4 * v);
            *reinterpret_cast<float4*>(obase + 4 * v) = w;
        }
        if (k < 7) __syncthreads();
    }
}

extern "C" void kernel_launch(void* const* d_in, const int* in_sizes, int n_in,
                              void* d_out, int out_size, void* d_ws, size_t ws_size,
                              hipStream_t stream) {
    const float* x   = (const float*)d_in[0];
    const float* sos = (const float*)d_in[1];
    const float* f2  = (const float*)d_in[2];
    const float* f3  = (const float*)d_in[3];
    float* out = (float*)d_out;

    conv1d_ell_kernel<<<dim3(1024), dim3(512), 0, stream>>>(x, f2, f3, out);

    // output 1: pass-through copy of sum_of_squares (16384 floats)
    hipMemcpyAsync(out + 113246208LL, sos, 16384 * sizeof(float),
                   hipMemcpyDeviceToDevice, stream);
}